// Round 11
// baseline (269.429 us; speedup 1.0000x reference)
//
#include <hip/hip_runtime.h>

#define DEVI __device__ __forceinline__

typedef __attribute__((ext_vector_type(8))) short bh8;    // 8 x bf16 (as raw shorts)
typedef __attribute__((ext_vector_type(4))) float f32x4;

static constexpr int Bsz  = 4;
static constexpr int Lseq = 2048;
static constexpr int INDIM = 1024;
static constexpr int NH = 16;
static constexpr int HD = 64;
static constexpr int QKVN = 3 * NH * HD;   // 3072
static constexpr int OUTD = 1024;
static constexpr int Mrows = Bsz * Lseq;   // 8192

DEVI unsigned short f2bf(float f) {
    unsigned u = __float_as_uint(f);
    u = u + 0x7fffu + ((u >> 16) & 1u);      // RNE
    return (unsigned short)(u >> 16);
}

// ---------------------------------------------------------------- convert X
__global__ __launch_bounds__(256) void convert_f32_bf16(
    const float* __restrict__ in, unsigned short* __restrict__ out, int n8) {
    int i = blockIdx.x * 256 + threadIdx.x;
    if (i >= n8) return;
    const f32x4* p = (const f32x4*)(in + (size_t)i * 8);
    f32x4 a = p[0], b = p[1];
    bh8 o;
    o[0] = (short)f2bf(a[0]); o[1] = (short)f2bf(a[1]);
    o[2] = (short)f2bf(a[2]); o[3] = (short)f2bf(a[3]);
    o[4] = (short)f2bf(b[0]); o[5] = (short)f2bf(b[1]);
    o[6] = (short)f2bf(b[2]); o[7] = (short)f2bf(b[3]);
    *(bh8*)(out + (size_t)i * 8) = o;
}

// ------------------------------------------- transpose W [K][N] -> Wt [N][K] bf16
__global__ __launch_bounds__(256) void transpose_f32_bf16(
    const float* __restrict__ W, unsigned short* __restrict__ Wt, int K, int N) {
    __shared__ unsigned short t[64][65];
    int n0 = blockIdx.x * 64, k0 = blockIdx.y * 64;
    int tid = threadIdx.x;
#pragma unroll
    for (int i = 0; i < 16; ++i) {
        int idx = tid + i * 256;
        int r = idx >> 6, c = idx & 63;
        t[r][c] = f2bf(W[(size_t)(k0 + r) * N + (n0 + c)]);
    }
    __syncthreads();
#pragma unroll
    for (int i = 0; i < 16; ++i) {
        int idx = tid + i * 256;
        int r = idx >> 6, c = idx & 63;
        Wt[(size_t)(n0 + r) * K + (k0 + c)] = t[c][r];
    }
}

// ---------------------------------------------------------------- GEMM C = A * Bt^T
// A [M][K] bf16, Bt [N][K] bf16. MODE 0: scatter to Q (pre-scaled by 1/8) /
// K bf16 [B*H][L][64] and V TRANSPOSED Vt [B*H][64][L]. MODE 1: f32 C [M][OUTD].
template <int MODE>
__global__ __launch_bounds__(256) void gemm_bt(
    const unsigned short* __restrict__ A, const unsigned short* __restrict__ Bt,
    float* __restrict__ Cf, unsigned short* __restrict__ Qg,
    unsigned short* __restrict__ Kg, unsigned short* __restrict__ Vg,
    int K, int ntn) {
    constexpr int PITCH = 40;                 // 32 + 8 pad, keeps 16B alignment
    __shared__ unsigned short Al[128 * PITCH];
    __shared__ unsigned short Bl[128 * PITCH];
    int tid = threadIdx.x;
    int lane = tid & 63, wave = tid >> 6;
    int mt = blockIdx.x / ntn, nt = blockIdx.x % ntn;
    int m0 = mt * 128, n0 = nt * 128;
    int wm = (wave >> 1) * 64, wn = (wave & 1) * 64;

    int srow = tid >> 2;                      // 0..63 staging row
    int skof = (tid & 3) * 8;                 // staging k offset (elements)
    const unsigned short* Ag = A + (size_t)(m0 + srow) * K + skof;
    const unsigned short* Bg = Bt + (size_t)(n0 + srow) * K + skof;
    unsigned short* Alw = Al + srow * PITCH + skof;
    unsigned short* Blw = Bl + srow * PITCH + skof;

    f32x4 acc[4][4] = {};
    int cl = lane & 15, kq = (lane >> 4) * 8;

    for (int k0 = 0; k0 < K; k0 += 32) {
        bh8 a0 = *(const bh8*)(Ag + k0);
        bh8 a1 = *(const bh8*)(Ag + (size_t)64 * K + k0);
        bh8 b0 = *(const bh8*)(Bg + k0);
        bh8 b1 = *(const bh8*)(Bg + (size_t)64 * K + k0);
        __syncthreads();                      // prior frag reads done before overwrite
        *(bh8*)(Alw) = a0;
        *(bh8*)(Alw + 64 * PITCH) = a1;
        *(bh8*)(Blw) = b0;
        *(bh8*)(Blw + 64 * PITCH) = b1;
        __syncthreads();
        bh8 af[4], bf[4];
#pragma unroll
        for (int mi = 0; mi < 4; ++mi)
            af[mi] = *(const bh8*)(Al + (wm + mi * 16 + cl) * PITCH + kq);
#pragma unroll
        for (int nj = 0; nj < 4; ++nj)
            bf[nj] = *(const bh8*)(Bl + (wn + nj * 16 + cl) * PITCH + kq);
#pragma unroll
        for (int mi = 0; mi < 4; ++mi)
#pragma unroll
            for (int nj = 0; nj < 4; ++nj)
                acc[mi][nj] = __builtin_amdgcn_mfma_f32_16x16x32_bf16(
                    af[mi], bf[nj], acc[mi][nj], 0, 0, 0);
    }

    int rb = (lane >> 4) * 4;
#pragma unroll
    for (int mi = 0; mi < 4; ++mi) {
#pragma unroll
        for (int nj = 0; nj < 4; ++nj) {
#pragma unroll
            for (int r = 0; r < 4; ++r) {
                int gm = m0 + wm + mi * 16 + rb + r;
                int gn = n0 + wn + nj * 16 + cl;
                float v = acc[mi][nj][r];
                if (MODE == 0) {
                    int b = gm >> 11, ls = gm & 2047;
                    int sel = gn >> 10, h = (gn >> 6) & 15, d = gn & 63;
                    if (sel == 0)   // Q pre-scaled by 1/sqrt(HD) (exact exp shift)
                        Qg[((size_t)(b * NH + h) * Lseq + ls) * HD + d] = f2bf(v * 0.125f);
                    else if (sel == 1)
                        Kg[((size_t)(b * NH + h) * Lseq + ls) * HD + d] = f2bf(v);
                    else  // V transposed: Vt[bh][d][kv]
                        Vg[((size_t)(b * NH + h) * HD + d) * Lseq + ls] = f2bf(v);
                } else {
                    Cf[(size_t)gm * OUTD + gn] = v;
                }
            }
        }
    }
}

// ---------------------------------------------------------------- causal flash attention
// Q (pre-scaled) / K bf16 [B*H][L][64]; Vt bf16 [B*H][64][L]; Og bf16 [B*L][H*64].
// 512 blocks x 512 threads (8 waves). Waves w and w+4 own the SAME 32 q-rows and
// split the kv-range in half (no-max softmax => o/osum are associative sums);
// merge via LDS + one barrier per pass. Two balanced passes over paired 128-row
// q-tiles (pr, 15-pr). XCD-affinity decode keeps each bh's blocks on one XCD L2.
__global__ __launch_bounds__(512) void attn_causal(
    const unsigned short* __restrict__ Qg, const unsigned short* __restrict__ Kg,
    const unsigned short* __restrict__ Vt, unsigned short* __restrict__ Og) {
    __shared__ unsigned short Pl[8][2][16 * 72];  // per-wave, per-frag P tile (36 KB)
    __shared__ float Ml[4][64][40];               // upper-half partials (40 KB)
    int tid = threadIdx.x, wave = tid >> 6, lane = tid & 63;
    int bid = blockIdx.x;
    // XCD-affinity decode: xcd = bid%8 (HW round-robin), bh%8 == xcd.
    int xcd = bid & 7, slot = bid >> 3;       // slot 0..63
    int pr = slot & 7;                        // pair index 0..7
    int bh = ((slot >> 3) << 3) | xcd;        // bh in 0..63, bh%8==xcd
    int b = bh >> 4, h = bh & 15;
    const unsigned short* Qp = Qg + (size_t)bh * Lseq * HD;
    const unsigned short* Kp = Kg + (size_t)bh * Lseq * HD;
    const unsigned short* Vp = Vt + (size_t)bh * HD * Lseq;   // [d][kv]
    int cl = lane & 15, kq = (lane >> 4) * 8, rb = (lane >> 4) * 4;
    int wsub = wave & 3;                      // row-group within tile
    int half = wave >> 2;                     // kv half: 0 = low, 1 = high

    bh8 ones;
#pragma unroll
    for (int i = 0; i < 8; ++i) ones[i] = (short)0x3F80;   // bf16 1.0

    for (int pass = 0; pass < 2; ++pass) {
        int qt = pass ? (15 - pr) : pr;
        int q0 = qt * 128 + wsub * 32;

        bh8 qf[2][2];
#pragma unroll
        for (int f = 0; f < 2; ++f) {
            qf[f][0] = *(const bh8*)(Qp + (size_t)(q0 + f * 16 + cl) * HD + kq);
            qf[f][1] = *(const bh8*)(Qp + (size_t)(q0 + f * 16 + cl) * HD + 32 + kq);
        }

        f32x4 o[2][4] = {};
        f32x4 osum[2] = {};                   // P row-sums via ones-MFMA

        int nblk = (q0 + 95) >> 6;            // kv-blocks covering diag for rows q0..q0+31
        int jmid = (nblk + 1) >> 1;
        int j0 = half ? jmid : 0;
        int j1 = half ? nblk : jmid;

        for (int j = j0; j < j1; ++j) {
            int kv0 = j * 64;
            // ---- QK^T: K fragments loaded once, used by both Q fragments
#pragma unroll
            for (int nb = 0; nb < 4; ++nb) {
                const unsigned short* Kb = Kp + (size_t)(kv0 + nb * 16 + cl) * HD + kq;
                bh8 kf0 = *(const bh8*)(Kb);
                bh8 kf1 = *(const bh8*)(Kb + 32);
#pragma unroll
                for (int f = 0; f < 2; ++f) {
                    f32x4 s = {};
                    s = __builtin_amdgcn_mfma_f32_16x16x32_bf16(qf[f][0], kf0, s, 0, 0, 0);
                    s = __builtin_amdgcn_mfma_f32_16x16x32_bf16(qf[f][1], kf1, s, 0, 0, 0);
                    int col = kv0 + nb * 16 + cl;
                    int rowb = q0 + f * 16 + rb;
                    unsigned short* Pw = &Pl[wave][f][0];
#pragma unroll
                    for (int r = 0; r < 4; ++r) {
                        float v = s[r];                   // Q pre-scaled by 1/8
                        if (col > rowb + r) v = -3e30f;   // causal mask (exp -> 0)
                        Pw[(rb + r) * 72 + nb * 16 + cl] = f2bf(__expf(v));
                    }
                }
            }
            // ---- P·V: V fragments contiguous from Vt, shared by both fragments
            bh8 pa[2][2];
#pragma unroll
            for (int f = 0; f < 2; ++f) {
                pa[f][0] = *(const bh8*)(&Pl[wave][f][0] + cl * 72 + kq);
                pa[f][1] = *(const bh8*)(&Pl[wave][f][0] + cl * 72 + 32 + kq);
            }
#pragma unroll
            for (int db = 0; db < 4; ++db) {
                const unsigned short* Vb = Vp + (size_t)(db * 16 + cl) * Lseq + kv0;
                bh8 vf0 = *(const bh8*)(Vb + kq);
                bh8 vf1 = *(const bh8*)(Vb + 32 + kq);
#pragma unroll
                for (int f = 0; f < 2; ++f) {
                    o[f][db] = __builtin_amdgcn_mfma_f32_16x16x32_bf16(pa[f][0], vf0, o[f][db], 0, 0, 0);
                    o[f][db] = __builtin_amdgcn_mfma_f32_16x16x32_bf16(pa[f][1], vf1, o[f][db], 0, 0, 0);
                }
            }
#pragma unroll
            for (int f = 0; f < 2; ++f) {
                osum[f] = __builtin_amdgcn_mfma_f32_16x16x32_bf16(pa[f][0], ones, osum[f], 0, 0, 0);
                osum[f] = __builtin_amdgcn_mfma_f32_16x16x32_bf16(pa[f][1], ones, osum[f], 0, 0, 0);
            }
        }

        // ---- merge the two kv halves through LDS, lower waves write output
        if (half) {
#pragma unroll
            for (int f = 0; f < 2; ++f) {
#pragma unroll
                for (int db = 0; db < 4; ++db)
#pragma unroll
                    for (int r = 0; r < 4; ++r)
                        Ml[wsub][lane][f * 16 + db * 4 + r] = o[f][db][r];
#pragma unroll
                for (int r = 0; r < 4; ++r)
                    Ml[wsub][lane][32 + f * 4 + r] = osum[f][r];
            }
        }
        __syncthreads();
        if (!half) {
#pragma unroll
            for (int f = 0; f < 2; ++f)
#pragma unroll
                for (int r = 0; r < 4; ++r) {
                    float stot = osum[f][r] + Ml[wsub][lane][32 + f * 4 + r];
                    float inv = 1.0f / stot;
                    int row = q0 + f * 16 + rb + r;
                    size_t obase = (size_t)(b * Lseq + row) * OUTD + h * HD;
#pragma unroll
                    for (int db = 0; db < 4; ++db) {
                        float ot = o[f][db][r] + Ml[wsub][lane][f * 16 + db * 4 + r];
                        Og[obase + db * 16 + cl] = f2bf(ot * inv);
                    }
                }
        }
        __syncthreads();                      // Ml safe to reuse next pass
    }
}

// ---------------------------------------------------------------- launch
extern "C" void kernel_launch(void* const* d_in, const int* in_sizes, int n_in,
                              void* d_out, int out_size, void* d_ws, size_t ws_size,
                              hipStream_t stream) {
    (void)in_sizes; (void)n_in; (void)out_size; (void)ws_size;
    const float* X    = (const float*)d_in[0];
    const float* Wqkv = (const float*)d_in[1];
    const float* Wout = (const float*)d_in[2];
    float* out = (float*)d_out;

    char* ws = (char*)d_ws;
    size_t off = 0;
    unsigned short* Xb    = (unsigned short*)(ws + off); off += (size_t)Mrows * INDIM * 2;
    unsigned short* WqkvT = (unsigned short*)(ws + off); off += (size_t)QKVN * INDIM * 2;
    unsigned short* WoutT = (unsigned short*)(ws + off); off += (size_t)OUTD * (NH * HD) * 2;
    unsigned short* Qg    = (unsigned short*)(ws + off); off += (size_t)Mrows * NH * HD * 2;
    unsigned short* Kg    = (unsigned short*)(ws + off); off += (size_t)Mrows * NH * HD * 2;
    unsigned short* Vtg   = (unsigned short*)(ws + off); off += (size_t)Mrows * NH * HD * 2;
    unsigned short* Ob    = (unsigned short*)(ws + off); off += (size_t)Mrows * NH * HD * 2;

    convert_f32_bf16<<<(Mrows * INDIM / 8 + 255) / 256, 256, 0, stream>>>(
        X, Xb, Mrows * INDIM / 8);
    transpose_f32_bf16<<<dim3(QKVN / 64, INDIM / 64), 256, 0, stream>>>(
        Wqkv, WqkvT, INDIM, QKVN);
    transpose_f32_bf16<<<dim3(OUTD / 64, (NH * HD) / 64), 256, 0, stream>>>(
        Wout, WoutT, NH * HD, OUTD);
    gemm_bt<0><<<(Mrows / 128) * (QKVN / 128), 256, 0, stream>>>(
        Xb, WqkvT, nullptr, Qg, Kg, Vtg, INDIM, QKVN / 128);
    attn_causal<<<Bsz * NH * 8, 512, 0, stream>>>(Qg, Kg, Vtg, Ob);
    gemm_bt<1><<<(Mrows / 128) * (OUTD / 128), 256, 0, stream>>>(
        Ob, WoutT, out, nullptr, nullptr, nullptr, NH * HD, OUTD / 128);
}

// Round 12
// 220.975 us; speedup vs baseline: 1.2193x; 1.2193x over previous
//
#include <hip/hip_runtime.h>

#define DEVI __device__ __forceinline__

typedef __attribute__((ext_vector_type(8))) short bh8;    // 8 x bf16 (as raw shorts)
typedef __attribute__((ext_vector_type(4))) float f32x4;

static constexpr int Bsz  = 4;
static constexpr int Lseq = 2048;
static constexpr int INDIM = 1024;
static constexpr int NH = 16;
static constexpr int HD = 64;
static constexpr int QKVN = 3 * NH * HD;   // 3072
static constexpr int OUTD = 1024;
static constexpr int Mrows = Bsz * Lseq;   // 8192

DEVI unsigned short f2bf(float f) {
    unsigned u = __float_as_uint(f);
    u = u + 0x7fffu + ((u >> 16) & 1u);      // RNE
    return (unsigned short)(u >> 16);
}

// ---------------------------------------------------------------- convert X
__global__ __launch_bounds__(256) void convert_f32_bf16(
    const float* __restrict__ in, unsigned short* __restrict__ out, int n8) {
    int i = blockIdx.x * 256 + threadIdx.x;
    if (i >= n8) return;
    const f32x4* p = (const f32x4*)(in + (size_t)i * 8);
    f32x4 a = p[0], b = p[1];
    bh8 o;
    o[0] = (short)f2bf(a[0]); o[1] = (short)f2bf(a[1]);
    o[2] = (short)f2bf(a[2]); o[3] = (short)f2bf(a[3]);
    o[4] = (short)f2bf(b[0]); o[5] = (short)f2bf(b[1]);
    o[6] = (short)f2bf(b[2]); o[7] = (short)f2bf(b[3]);
    *(bh8*)(out + (size_t)i * 8) = o;
}

// ------------------------------------------- transpose W [K][N] -> Wt [N][K] bf16
__global__ __launch_bounds__(256) void transpose_f32_bf16(
    const float* __restrict__ W, unsigned short* __restrict__ Wt, int K, int N) {
    __shared__ unsigned short t[64][65];
    int n0 = blockIdx.x * 64, k0 = blockIdx.y * 64;
    int tid = threadIdx.x;
#pragma unroll
    for (int i = 0; i < 16; ++i) {
        int idx = tid + i * 256;
        int r = idx >> 6, c = idx & 63;
        t[r][c] = f2bf(W[(size_t)(k0 + r) * N + (n0 + c)]);
    }
    __syncthreads();
#pragma unroll
    for (int i = 0; i < 16; ++i) {
        int idx = tid + i * 256;
        int r = idx >> 6, c = idx & 63;
        Wt[(size_t)(n0 + r) * K + (k0 + c)] = t[c][r];
    }
}

// ---------------------------------------------------------------- GEMM C = A * Bt^T
// A [M][K] bf16, Bt [N][K] bf16. MODE 0: scatter to Q (pre-scaled by 1/8) /
// K bf16 [B*H][L][64] and V TRANSPOSED Vt [B*H][64][L]. MODE 1: f32 C [M][OUTD].
template <int MODE>
__global__ __launch_bounds__(256) void gemm_bt(
    const unsigned short* __restrict__ A, const unsigned short* __restrict__ Bt,
    float* __restrict__ Cf, unsigned short* __restrict__ Qg,
    unsigned short* __restrict__ Kg, unsigned short* __restrict__ Vg,
    int K, int ntn) {
    constexpr int PITCH = 40;                 // 32 + 8 pad, keeps 16B alignment
    __shared__ unsigned short Al[128 * PITCH];
    __shared__ unsigned short Bl[128 * PITCH];
    int tid = threadIdx.x;
    int lane = tid & 63, wave = tid >> 6;
    int mt = blockIdx.x / ntn, nt = blockIdx.x % ntn;
    int m0 = mt * 128, n0 = nt * 128;
    int wm = (wave >> 1) * 64, wn = (wave & 1) * 64;

    int srow = tid >> 2;                      // 0..63 staging row
    int skof = (tid & 3) * 8;                 // staging k offset (elements)
    const unsigned short* Ag = A + (size_t)(m0 + srow) * K + skof;
    const unsigned short* Bg = Bt + (size_t)(n0 + srow) * K + skof;
    unsigned short* Alw = Al + srow * PITCH + skof;
    unsigned short* Blw = Bl + srow * PITCH + skof;

    f32x4 acc[4][4] = {};
    int cl = lane & 15, kq = (lane >> 4) * 8;

    for (int k0 = 0; k0 < K; k0 += 32) {
        bh8 a0 = *(const bh8*)(Ag + k0);
        bh8 a1 = *(const bh8*)(Ag + (size_t)64 * K + k0);
        bh8 b0 = *(const bh8*)(Bg + k0);
        bh8 b1 = *(const bh8*)(Bg + (size_t)64 * K + k0);
        __syncthreads();                      // prior frag reads done before overwrite
        *(bh8*)(Alw) = a0;
        *(bh8*)(Alw + 64 * PITCH) = a1;
        *(bh8*)(Blw) = b0;
        *(bh8*)(Blw + 64 * PITCH) = b1;
        __syncthreads();
        bh8 af[4], bf[4];
#pragma unroll
        for (int mi = 0; mi < 4; ++mi)
            af[mi] = *(const bh8*)(Al + (wm + mi * 16 + cl) * PITCH + kq);
#pragma unroll
        for (int nj = 0; nj < 4; ++nj)
            bf[nj] = *(const bh8*)(Bl + (wn + nj * 16 + cl) * PITCH + kq);
#pragma unroll
        for (int mi = 0; mi < 4; ++mi)
#pragma unroll
            for (int nj = 0; nj < 4; ++nj)
                acc[mi][nj] = __builtin_amdgcn_mfma_f32_16x16x32_bf16(
                    af[mi], bf[nj], acc[mi][nj], 0, 0, 0);
    }

    int rb = (lane >> 4) * 4;
#pragma unroll
    for (int mi = 0; mi < 4; ++mi) {
#pragma unroll
        for (int nj = 0; nj < 4; ++nj) {
#pragma unroll
            for (int r = 0; r < 4; ++r) {
                int gm = m0 + wm + mi * 16 + rb + r;
                int gn = n0 + wn + nj * 16 + cl;
                float v = acc[mi][nj][r];
                if (MODE == 0) {
                    int b = gm >> 11, ls = gm & 2047;
                    int sel = gn >> 10, h = (gn >> 6) & 15, d = gn & 63;
                    if (sel == 0)   // Q pre-scaled by 1/sqrt(HD) (exact exp shift)
                        Qg[((size_t)(b * NH + h) * Lseq + ls) * HD + d] = f2bf(v * 0.125f);
                    else if (sel == 1)
                        Kg[((size_t)(b * NH + h) * Lseq + ls) * HD + d] = f2bf(v);
                    else  // V transposed: Vt[bh][d][kv]
                        Vg[((size_t)(b * NH + h) * HD + d) * Lseq + ls] = f2bf(v);
                } else {
                    Cf[(size_t)gm * OUTD + gn] = v;
                }
            }
        }
    }
}

// ---------------------------------------------------------------- causal flash attention
// Q (pre-scaled) / K bf16 [B*H][L][64]; Vt bf16 [B*H][64][L]; Og bf16 [B*L][H*64].
// 1024 blocks x 256 threads. Block = pair of 64-row q-tiles (p, 31-p), two
// sequential passes (uniform ~17 kv-units/block). Per kv-block j: K and V tiles
// are cooperatively staged into LDS with COALESCED full-line loads (fixes the
// per-CU TA saturation from 128B-stride fragment gathers, R11 post-mortem);
// fragments then come from LDS via swizzled ds_read_b128 (XOR swizzle
// elem ^= (row&7)<<3 on write AND read; ~2-way residual conflicts = free).
// No-max softmax + ones-MFMA row-sum (verified R9-R11). XCD-affinity decode.
// nblk = p+1 is uniform across the 4 waves (16 rows each) -> no divergence.
__global__ __launch_bounds__(256) void attn_causal(
    const unsigned short* __restrict__ Qg, const unsigned short* __restrict__ Kg,
    const unsigned short* __restrict__ Vt, unsigned short* __restrict__ Og) {
    __shared__ unsigned short Kl[64 * 64];        // 8 KB, swizzled rows
    __shared__ unsigned short Vl[64 * 64];        // 8 KB, swizzled rows
    __shared__ unsigned short Pl[4][16 * 72];     // per-wave P tile (9 KB)
    int tid = threadIdx.x, wave = tid >> 6, lane = tid & 63;
    int bid = blockIdx.x;
    // XCD-affinity decode: xcd = bid%8 (HW round-robin), bh%8 == xcd.
    int xcd = bid & 7, slot = bid >> 3;       // slot 0..127
    int p = slot & 15;                        // pair index 0..15
    int bh = ((slot >> 4) << 3) | xcd;        // bh in 0..63, bh%8==xcd
    int b = bh >> 4, h = bh & 15;
    const unsigned short* Qp = Qg + (size_t)bh * Lseq * HD;
    const unsigned short* Kp = Kg + (size_t)bh * Lseq * HD;
    const unsigned short* Vp = Vt + (size_t)bh * HD * Lseq;   // [d][kv]
    int cl = lane & 15, kq = (lane >> 4) * 8, rb = (lane >> 4) * 4;
    unsigned short* Pw = &Pl[wave][0];

    int srow = tid >> 2;                      // staging row 0..63
    int sc0 = (tid & 3) * 16;                 // element chunk base (2x 8-elem chunks)
    int ssw = (srow & 7) << 3;                // write-side swizzle (elements)

    bh8 ones;
#pragma unroll
    for (int i = 0; i < 8; ++i) ones[i] = (short)0x3F80;   // bf16 1.0

    for (int pass = 0; pass < 2; ++pass) {
        int pt = pass ? (31 - p) : p;
        int q0 = pt * 64 + wave * 16;         // this wave's 16 rows

        bh8 qf0 = *(const bh8*)(Qp + (size_t)(q0 + cl) * HD + kq);
        bh8 qf1 = *(const bh8*)(Qp + (size_t)(q0 + cl) * HD + 32 + kq);

        f32x4 o[4] = {};
        f32x4 osum = {};                      // P row-sums via ones-MFMA

        int nblk = pt + 1;                    // uniform across waves
        for (int j = 0; j < nblk; ++j) {
            int kv0 = j * 64;
            // ---- coalesced cooperative staging of K and V blocks
            const unsigned short* Ks = Kp + (size_t)(kv0 + srow) * HD;
            const unsigned short* Vs = Vp + (size_t)srow * Lseq + kv0;
            bh8 k0 = *(const bh8*)(Ks + sc0);
            bh8 k1 = *(const bh8*)(Ks + sc0 + 8);
            bh8 v0 = *(const bh8*)(Vs + sc0);
            bh8 v1 = *(const bh8*)(Vs + sc0 + 8);
            __syncthreads();                  // prior iter's frag reads done
            *(bh8*)(Kl + srow * 64 + (sc0 ^ ssw)) = k0;
            *(bh8*)(Kl + srow * 64 + ((sc0 + 8) ^ ssw)) = k1;
            *(bh8*)(Vl + srow * 64 + (sc0 ^ ssw)) = v0;
            *(bh8*)(Vl + srow * 64 + ((sc0 + 8) ^ ssw)) = v1;
            __syncthreads();
            // ---- QK^T from LDS
#pragma unroll
            for (int nb = 0; nb < 4; ++nb) {
                int row = nb * 16 + cl, rs = (row & 7) << 3;
                bh8 kf0 = *(const bh8*)(Kl + row * 64 + (kq ^ rs));
                bh8 kf1 = *(const bh8*)(Kl + row * 64 + ((kq + 32) ^ rs));
                f32x4 s = {};
                s = __builtin_amdgcn_mfma_f32_16x16x32_bf16(qf0, kf0, s, 0, 0, 0);
                s = __builtin_amdgcn_mfma_f32_16x16x32_bf16(qf1, kf1, s, 0, 0, 0);
                int col = kv0 + nb * 16 + cl;
#pragma unroll
                for (int r = 0; r < 4; ++r) {
                    float v = s[r];                   // Q pre-scaled by 1/8
                    if (col > q0 + rb + r) v = -3e30f;    // causal mask
                    Pw[(rb + r) * 72 + nb * 16 + cl] = f2bf(__expf(v));
                }
            }
            // ---- P·V from LDS
            bh8 pa0 = *(const bh8*)(Pw + cl * 72 + kq);
            bh8 pa1 = *(const bh8*)(Pw + cl * 72 + 32 + kq);
#pragma unroll
            for (int db = 0; db < 4; ++db) {
                int dr = db * 16 + cl, ds = (dr & 7) << 3;
                bh8 vf0 = *(const bh8*)(Vl + dr * 64 + (kq ^ ds));
                bh8 vf1 = *(const bh8*)(Vl + dr * 64 + ((kq + 32) ^ ds));
                o[db] = __builtin_amdgcn_mfma_f32_16x16x32_bf16(pa0, vf0, o[db], 0, 0, 0);
                o[db] = __builtin_amdgcn_mfma_f32_16x16x32_bf16(pa1, vf1, o[db], 0, 0, 0);
            }
            osum = __builtin_amdgcn_mfma_f32_16x16x32_bf16(pa0, ones, osum, 0, 0, 0);
            osum = __builtin_amdgcn_mfma_f32_16x16x32_bf16(pa1, ones, osum, 0, 0, 0);
        }
#pragma unroll
        for (int r = 0; r < 4; ++r) {
            float inv = 1.0f / osum[r];
            int row = q0 + rb + r;
            size_t obase = (size_t)(b * Lseq + row) * OUTD + h * HD;
#pragma unroll
            for (int db = 0; db < 4; ++db)
                Og[obase + db * 16 + cl] = f2bf(o[db][r] * inv);
        }
    }
}

// ---------------------------------------------------------------- launch
extern "C" void kernel_launch(void* const* d_in, const int* in_sizes, int n_in,
                              void* d_out, int out_size, void* d_ws, size_t ws_size,
                              hipStream_t stream) {
    (void)in_sizes; (void)n_in; (void)out_size; (void)ws_size;
    const float* X    = (const float*)d_in[0];
    const float* Wqkv = (const float*)d_in[1];
    const float* Wout = (const float*)d_in[2];
    float* out = (float*)d_out;

    char* ws = (char*)d_ws;
    size_t off = 0;
    unsigned short* Xb    = (unsigned short*)(ws + off); off += (size_t)Mrows * INDIM * 2;
    unsigned short* WqkvT = (unsigned short*)(ws + off); off += (size_t)QKVN * INDIM * 2;
    unsigned short* WoutT = (unsigned short*)(ws + off); off += (size_t)OUTD * (NH * HD) * 2;
    unsigned short* Qg    = (unsigned short*)(ws + off); off += (size_t)Mrows * NH * HD * 2;
    unsigned short* Kg    = (unsigned short*)(ws + off); off += (size_t)Mrows * NH * HD * 2;
    unsigned short* Vtg   = (unsigned short*)(ws + off); off += (size_t)Mrows * NH * HD * 2;
    unsigned short* Ob    = (unsigned short*)(ws + off); off += (size_t)Mrows * NH * HD * 2;

    convert_f32_bf16<<<(Mrows * INDIM / 8 + 255) / 256, 256, 0, stream>>>(
        X, Xb, Mrows * INDIM / 8);
    transpose_f32_bf16<<<dim3(QKVN / 64, INDIM / 64), 256, 0, stream>>>(
        Wqkv, WqkvT, INDIM, QKVN);
    transpose_f32_bf16<<<dim3(OUTD / 64, (NH * HD) / 64), 256, 0, stream>>>(
        Wout, WoutT, NH * HD, OUTD);
    gemm_bt<0><<<(Mrows / 128) * (QKVN / 128), 256, 0, stream>>>(
        Xb, WqkvT, nullptr, Qg, Kg, Vtg, INDIM, QKVN / 128);
    attn_causal<<<Bsz * NH * 16, 256, 0, stream>>>(Qg, Kg, Vtg, Ob);
    gemm_bt<1><<<(Mrows / 128) * (OUTD / 128), 256, 0, stream>>>(
        Ob, WoutT, out, nullptr, nullptr, nullptr, NH * HD, OUTD / 128);
}

// Round 13
// 217.906 us; speedup vs baseline: 1.2364x; 1.0141x over previous
//
#include <hip/hip_runtime.h>

#define DEVI __device__ __forceinline__

typedef __attribute__((ext_vector_type(8))) short bh8;    // 8 x bf16 (as raw shorts)
typedef __attribute__((ext_vector_type(4))) float f32x4;

static constexpr int Bsz  = 4;
static constexpr int Lseq = 2048;
static constexpr int INDIM = 1024;
static constexpr int NH = 16;
static constexpr int HD = 64;
static constexpr int QKVN = 3 * NH * HD;   // 3072
static constexpr int OUTD = 1024;
static constexpr int Mrows = Bsz * Lseq;   // 8192

DEVI unsigned short f2bf(float f) {
    unsigned u = __float_as_uint(f);
    u = u + 0x7fffu + ((u >> 16) & 1u);      // RNE
    return (unsigned short)(u >> 16);
}

// async global->LDS, 16 bytes per lane (HW: wave-uniform LDS base + lane*16)
DEVI void gl2lds16(const unsigned short* g, unsigned short* l) {
    __builtin_amdgcn_global_load_lds(
        (const __attribute__((address_space(1))) void*)g,
        (__attribute__((address_space(3))) void*)l, 16, 0, 0);
}

// ---------------------------------------------------------------- convert X
__global__ __launch_bounds__(256) void convert_f32_bf16(
    const float* __restrict__ in, unsigned short* __restrict__ out, int n8) {
    int i = blockIdx.x * 256 + threadIdx.x;
    if (i >= n8) return;
    const f32x4* p = (const f32x4*)(in + (size_t)i * 8);
    f32x4 a = p[0], b = p[1];
    bh8 o;
    o[0] = (short)f2bf(a[0]); o[1] = (short)f2bf(a[1]);
    o[2] = (short)f2bf(a[2]); o[3] = (short)f2bf(a[3]);
    o[4] = (short)f2bf(b[0]); o[5] = (short)f2bf(b[1]);
    o[6] = (short)f2bf(b[2]); o[7] = (short)f2bf(b[3]);
    *(bh8*)(out + (size_t)i * 8) = o;
}

// ------------------------------------------- transpose W [K][N] -> Wt [N][K] bf16
__global__ __launch_bounds__(256) void transpose_f32_bf16(
    const float* __restrict__ W, unsigned short* __restrict__ Wt, int K, int N) {
    __shared__ unsigned short t[64][65];
    int n0 = blockIdx.x * 64, k0 = blockIdx.y * 64;
    int tid = threadIdx.x;
#pragma unroll
    for (int i = 0; i < 16; ++i) {
        int idx = tid + i * 256;
        int r = idx >> 6, c = idx & 63;
        t[r][c] = f2bf(W[(size_t)(k0 + r) * N + (n0 + c)]);
    }
    __syncthreads();
#pragma unroll
    for (int i = 0; i < 16; ++i) {
        int idx = tid + i * 256;
        int r = idx >> 6, c = idx & 63;
        Wt[(size_t)(n0 + r) * K + (k0 + c)] = t[c][r];
    }
}

// ---------------------------------------------------------------- GEMM C = A * Bt^T
// A [M][K] bf16, Bt [N][K] bf16. Staging via global_load_lds width=16 (m97
// structure): linear LDS [128][32], dest offset = wave*1024B + lane*16B.
// MODE 0: scatter to Q (pre-scaled by 1/8) / K bf16 [B*H][L][64] and
// V TRANSPOSED Vt [B*H][64][L]. MODE 1: f32 C [M][OUTD].
template <int MODE>
__global__ __launch_bounds__(256) void gemm_bt(
    const unsigned short* __restrict__ A, const unsigned short* __restrict__ Bt,
    float* __restrict__ Cf, unsigned short* __restrict__ Qg,
    unsigned short* __restrict__ Kg, unsigned short* __restrict__ Vg,
    int K, int ntn) {
    __shared__ unsigned short Al[128 * 32];   // 8 KB, linear rows (64 B)
    __shared__ unsigned short Bl[128 * 32];   // 8 KB
    int tid = threadIdx.x;
    int lane = tid & 63, wave = tid >> 6;
    int mt = blockIdx.x / ntn, nt = blockIdx.x % ntn;
    int m0 = mt * 128, n0 = nt * 128;
    int wm = (wave >> 1) * 64, wn = (wave & 1) * 64;

    int srow = tid >> 2;                      // 0..63 staging row
    int skof = (tid & 3) * 8;                 // staging k offset (elements)
    const unsigned short* Ags = A + (size_t)(m0 + srow) * K + skof;
    const unsigned short* Bgs = Bt + (size_t)(n0 + srow) * K + skof;
    // wave-uniform LDS bases (HW writes lane l at base + l*16B)
    unsigned short* a0 = Al + wave * 512;          // rows 0..63
    unsigned short* a1 = Al + 2048 + wave * 512;   // rows 64..127
    unsigned short* b0 = Bl + wave * 512;
    unsigned short* b1 = Bl + 2048 + wave * 512;

    f32x4 acc[4][4] = {};
    int cl = lane & 15, kq = (lane >> 4) * 8;

    for (int k0 = 0; k0 < K; k0 += 32) {
        __syncthreads();                      // prior frag reads done before overwrite
        gl2lds16(Ags + k0, a0);
        gl2lds16(Ags + (size_t)64 * K + k0, a1);
        gl2lds16(Bgs + k0, b0);
        gl2lds16(Bgs + (size_t)64 * K + k0, b1);
        __syncthreads();                      // drains vmcnt -> LDS visible
        bh8 af[4], bf[4];
#pragma unroll
        for (int mi = 0; mi < 4; ++mi)
            af[mi] = *(const bh8*)(Al + (wm + mi * 16 + cl) * 32 + kq);
#pragma unroll
        for (int nj = 0; nj < 4; ++nj)
            bf[nj] = *(const bh8*)(Bl + (wn + nj * 16 + cl) * 32 + kq);
#pragma unroll
        for (int mi = 0; mi < 4; ++mi)
#pragma unroll
            for (int nj = 0; nj < 4; ++nj)
                acc[mi][nj] = __builtin_amdgcn_mfma_f32_16x16x32_bf16(
                    af[mi], bf[nj], acc[mi][nj], 0, 0, 0);
    }

    int rb = (lane >> 4) * 4;
#pragma unroll
    for (int mi = 0; mi < 4; ++mi) {
#pragma unroll
        for (int nj = 0; nj < 4; ++nj) {
#pragma unroll
            for (int r = 0; r < 4; ++r) {
                int gm = m0 + wm + mi * 16 + rb + r;
                int gn = n0 + wn + nj * 16 + cl;
                float v = acc[mi][nj][r];
                if (MODE == 0) {
                    int b = gm >> 11, ls = gm & 2047;
                    int sel = gn >> 10, h = (gn >> 6) & 15, d = gn & 63;
                    if (sel == 0)   // Q pre-scaled by 1/sqrt(HD) (exact exp shift)
                        Qg[((size_t)(b * NH + h) * Lseq + ls) * HD + d] = f2bf(v * 0.125f);
                    else if (sel == 1)
                        Kg[((size_t)(b * NH + h) * Lseq + ls) * HD + d] = f2bf(v);
                    else  // V transposed: Vt[bh][d][kv]
                        Vg[((size_t)(b * NH + h) * HD + d) * Lseq + ls] = f2bf(v);
                } else {
                    Cf[(size_t)gm * OUTD + gn] = v;
                }
            }
        }
    }
}

// ---------------------------------------------------------------- causal flash attention
// (unchanged from R12 — verified: LDS-staged K/V, XOR swizzle both sides,
// no-max softmax + ones-MFMA row-sum, XCD-affinity decode, paired tiles)
__global__ __launch_bounds__(256) void attn_causal(
    const unsigned short* __restrict__ Qg, const unsigned short* __restrict__ Kg,
    const unsigned short* __restrict__ Vt, unsigned short* __restrict__ Og) {
    __shared__ unsigned short Kl[64 * 64];        // 8 KB, swizzled rows
    __shared__ unsigned short Vl[64 * 64];        // 8 KB, swizzled rows
    __shared__ unsigned short Pl[4][16 * 72];     // per-wave P tile (9 KB)
    int tid = threadIdx.x, wave = tid >> 6, lane = tid & 63;
    int bid = blockIdx.x;
    int xcd = bid & 7, slot = bid >> 3;       // slot 0..127
    int p = slot & 15;                        // pair index 0..15
    int bh = ((slot >> 4) << 3) | xcd;        // bh in 0..63, bh%8==xcd
    int b = bh >> 4, h = bh & 15;
    const unsigned short* Qp = Qg + (size_t)bh * Lseq * HD;
    const unsigned short* Kp = Kg + (size_t)bh * Lseq * HD;
    const unsigned short* Vp = Vt + (size_t)bh * HD * Lseq;   // [d][kv]
    int cl = lane & 15, kq = (lane >> 4) * 8, rb = (lane >> 4) * 4;
    unsigned short* Pw = &Pl[wave][0];

    int srow = tid >> 2;                      // staging row 0..63
    int sc0 = (tid & 3) * 16;                 // element chunk base
    int ssw = (srow & 7) << 3;                // write-side swizzle (elements)

    bh8 ones;
#pragma unroll
    for (int i = 0; i < 8; ++i) ones[i] = (short)0x3F80;   // bf16 1.0

    for (int pass = 0; pass < 2; ++pass) {
        int pt = pass ? (31 - p) : p;
        int q0 = pt * 64 + wave * 16;         // this wave's 16 rows

        bh8 qf0 = *(const bh8*)(Qp + (size_t)(q0 + cl) * HD + kq);
        bh8 qf1 = *(const bh8*)(Qp + (size_t)(q0 + cl) * HD + 32 + kq);

        f32x4 o[4] = {};
        f32x4 osum = {};                      // P row-sums via ones-MFMA

        int nblk = pt + 1;                    // uniform across waves
        for (int j = 0; j < nblk; ++j) {
            int kv0 = j * 64;
            const unsigned short* Ks = Kp + (size_t)(kv0 + srow) * HD;
            const unsigned short* Vs = Vp + (size_t)srow * Lseq + kv0;
            bh8 k0 = *(const bh8*)(Ks + sc0);
            bh8 k1 = *(const bh8*)(Ks + sc0 + 8);
            bh8 v0 = *(const bh8*)(Vs + sc0);
            bh8 v1 = *(const bh8*)(Vs + sc0 + 8);
            __syncthreads();                  // prior iter's frag reads done
            *(bh8*)(Kl + srow * 64 + (sc0 ^ ssw)) = k0;
            *(bh8*)(Kl + srow * 64 + ((sc0 + 8) ^ ssw)) = k1;
            *(bh8*)(Vl + srow * 64 + (sc0 ^ ssw)) = v0;
            *(bh8*)(Vl + srow * 64 + ((sc0 + 8) ^ ssw)) = v1;
            __syncthreads();
#pragma unroll
            for (int nb = 0; nb < 4; ++nb) {
                int row = nb * 16 + cl, rs = (row & 7) << 3;
                bh8 kf0 = *(const bh8*)(Kl + row * 64 + (kq ^ rs));
                bh8 kf1 = *(const bh8*)(Kl + row * 64 + ((kq + 32) ^ rs));
                f32x4 s = {};
                s = __builtin_amdgcn_mfma_f32_16x16x32_bf16(qf0, kf0, s, 0, 0, 0);
                s = __builtin_amdgcn_mfma_f32_16x16x32_bf16(qf1, kf1, s, 0, 0, 0);
                int col = kv0 + nb * 16 + cl;
#pragma unroll
                for (int r = 0; r < 4; ++r) {
                    float v = s[r];                   // Q pre-scaled by 1/8
                    if (col > q0 + rb + r) v = -3e30f;    // causal mask
                    Pw[(rb + r) * 72 + nb * 16 + cl] = f2bf(__expf(v));
                }
            }
            bh8 pa0 = *(const bh8*)(Pw + cl * 72 + kq);
            bh8 pa1 = *(const bh8*)(Pw + cl * 72 + 32 + kq);
#pragma unroll
            for (int db = 0; db < 4; ++db) {
                int dr = db * 16 + cl, ds = (dr & 7) << 3;
                bh8 vf0 = *(const bh8*)(Vl + dr * 64 + (kq ^ ds));
                bh8 vf1 = *(const bh8*)(Vl + dr * 64 + ((kq + 32) ^ ds));
                o[db] = __builtin_amdgcn_mfma_f32_16x16x32_bf16(pa0, vf0, o[db], 0, 0, 0);
                o[db] = __builtin_amdgcn_mfma_f32_16x16x32_bf16(pa1, vf1, o[db], 0, 0, 0);
            }
            osum = __builtin_amdgcn_mfma_f32_16x16x32_bf16(pa0, ones, osum, 0, 0, 0);
            osum = __builtin_amdgcn_mfma_f32_16x16x32_bf16(pa1, ones, osum, 0, 0, 0);
        }
#pragma unroll
        for (int r = 0; r < 4; ++r) {
            float inv = 1.0f / osum[r];
            int row = q0 + rb + r;
            size_t obase = (size_t)(b * Lseq + row) * OUTD + h * HD;
#pragma unroll
            for (int db = 0; db < 4; ++db)
                Og[obase + db * 16 + cl] = f2bf(o[db][r] * inv);
        }
    }
}

// ---------------------------------------------------------------- launch
extern "C" void kernel_launch(void* const* d_in, const int* in_sizes, int n_in,
                              void* d_out, int out_size, void* d_ws, size_t ws_size,
                              hipStream_t stream) {
    (void)in_sizes; (void)n_in; (void)out_size; (void)ws_size;
    const float* X    = (const float*)d_in[0];
    const float* Wqkv = (const float*)d_in[1];
    const float* Wout = (const float*)d_in[2];
    float* out = (float*)d_out;

    char* ws = (char*)d_ws;
    size_t off = 0;
    unsigned short* Xb    = (unsigned short*)(ws + off); off += (size_t)Mrows * INDIM * 2;
    unsigned short* WqkvT = (unsigned short*)(ws + off); off += (size_t)QKVN * INDIM * 2;
    unsigned short* WoutT = (unsigned short*)(ws + off); off += (size_t)OUTD * (NH * HD) * 2;
    unsigned short* Qg    = (unsigned short*)(ws + off); off += (size_t)Mrows * NH * HD * 2;
    unsigned short* Kg    = (unsigned short*)(ws + off); off += (size_t)Mrows * NH * HD * 2;
    unsigned short* Vtg   = (unsigned short*)(ws + off); off += (size_t)Mrows * NH * HD * 2;
    unsigned short* Ob    = (unsigned short*)(ws + off); off += (size_t)Mrows * NH * HD * 2;

    convert_f32_bf16<<<(Mrows * INDIM / 8 + 255) / 256, 256, 0, stream>>>(
        X, Xb, Mrows * INDIM / 8);
    transpose_f32_bf16<<<dim3(QKVN / 64, INDIM / 64), 256, 0, stream>>>(
        Wqkv, WqkvT, INDIM, QKVN);
    transpose_f32_bf16<<<dim3(OUTD / 64, (NH * HD) / 64), 256, 0, stream>>>(
        Wout, WoutT, NH * HD, OUTD);
    gemm_bt<0><<<(Mrows / 128) * (QKVN / 128), 256, 0, stream>>>(
        Xb, WqkvT, nullptr, Qg, Kg, Vtg, INDIM, QKVN / 128);
    attn_causal<<<Bsz * NH * 16, 256, 0, stream>>>(Qg, Kg, Vtg, Ob);
    gemm_bt<1><<<(Mrows / 128) * (OUTD / 128), 256, 0, stream>>>(
        Ob, WoutT, out, nullptr, nullptr, nullptr, NH * HD, OUTD / 128);
}

// Round 14
// 209.474 us; speedup vs baseline: 1.2862x; 1.0403x over previous
//
#include <hip/hip_runtime.h>

#define DEVI __device__ __forceinline__

typedef __attribute__((ext_vector_type(8))) short bh8;    // 8 x bf16 (as raw shorts)
typedef __attribute__((ext_vector_type(4))) float f32x4;

static constexpr int Bsz  = 4;
static constexpr int Lseq = 2048;
static constexpr int INDIM = 1024;
static constexpr int NH = 16;
static constexpr int HD = 64;
static constexpr int QKVN = 3 * NH * HD;   // 3072
static constexpr int OUTD = 1024;
static constexpr int Mrows = Bsz * Lseq;   // 8192

DEVI unsigned short f2bf(float f) {
    unsigned u = __float_as_uint(f);
    u = u + 0x7fffu + ((u >> 16) & 1u);      // RNE
    return (unsigned short)(u >> 16);
}

// async global->LDS, 16 bytes per lane (HW: wave-uniform LDS base + lane*16)
DEVI void gl2lds16(const unsigned short* g, unsigned short* l) {
    __builtin_amdgcn_global_load_lds(
        (const __attribute__((address_space(1))) void*)g,
        (__attribute__((address_space(3))) void*)l, 16, 0, 0);
}

// ---------------------------------------------------------------- convert X
__global__ __launch_bounds__(256) void convert_f32_bf16(
    const float* __restrict__ in, unsigned short* __restrict__ out, int n8) {
    int i = blockIdx.x * 256 + threadIdx.x;
    if (i >= n8) return;
    const f32x4* p = (const f32x4*)(in + (size_t)i * 8);
    f32x4 a = p[0], b = p[1];
    bh8 o;
    o[0] = (short)f2bf(a[0]); o[1] = (short)f2bf(a[1]);
    o[2] = (short)f2bf(a[2]); o[3] = (short)f2bf(a[3]);
    o[4] = (short)f2bf(b[0]); o[5] = (short)f2bf(b[1]);
    o[6] = (short)f2bf(b[2]); o[7] = (short)f2bf(b[3]);
    *(bh8*)(out + (size_t)i * 8) = o;
}

// ------------------------------------------- transpose W [K][N] -> Wt [N][K] bf16
__global__ __launch_bounds__(256) void transpose_f32_bf16(
    const float* __restrict__ W, unsigned short* __restrict__ Wt, int K, int N) {
    __shared__ unsigned short t[64][65];
    int n0 = blockIdx.x * 64, k0 = blockIdx.y * 64;
    int tid = threadIdx.x;
#pragma unroll
    for (int i = 0; i < 16; ++i) {
        int idx = tid + i * 256;
        int r = idx >> 6, c = idx & 63;
        t[r][c] = f2bf(W[(size_t)(k0 + r) * N + (n0 + c)]);
    }
    __syncthreads();
#pragma unroll
    for (int i = 0; i < 16; ++i) {
        int idx = tid + i * 256;
        int r = idx >> 6, c = idx & 63;
        Wt[(size_t)(n0 + r) * K + (k0 + c)] = t[c][r];
    }
}

// ---------------------------------------------------------------- GEMM C = A * Bt^T
// A [M][K] bf16, Bt [N][K] bf16. global_load_lds width=16 staging with
// DOUBLE-BUFFERED LDS + prefetch (T3 minimum 2-phase): stage tile t+1 BEFORE
// computing tile t; single __syncthreads per iter (vmcnt+lgkm drain).
// MODE 0: scatter to Q (pre-scaled by 1/8) / K bf16 [B*H][L][64] and
// V TRANSPOSED Vt [B*H][64][L]. MODE 1: f32 C [M][OUTD].
template <int MODE>
__global__ __launch_bounds__(256) void gemm_bt(
    const unsigned short* __restrict__ A, const unsigned short* __restrict__ Bt,
    float* __restrict__ Cf, unsigned short* __restrict__ Qg,
    unsigned short* __restrict__ Kg, unsigned short* __restrict__ Vg,
    int K, int ntn) {
    __shared__ unsigned short Al[2][128 * 32];   // 2 x 8 KB, linear rows (64 B)
    __shared__ unsigned short Bl[2][128 * 32];
    int tid = threadIdx.x;
    int lane = tid & 63, wave = tid >> 6;
    int mt = blockIdx.x / ntn, nt_ = blockIdx.x % ntn;
    int m0 = mt * 128, n0 = nt_ * 128;
    int wm = (wave >> 1) * 64, wn = (wave & 1) * 64;

    int srow = tid >> 2;                      // 0..63 staging row
    int skof = (tid & 3) * 8;                 // staging k offset (elements)
    const unsigned short* Ags = A + (size_t)(m0 + srow) * K + skof;
    const unsigned short* Bgs = Bt + (size_t)(n0 + srow) * K + skof;
    int wofs = wave * 512;                    // wave-uniform LDS base (elements)

    f32x4 acc[4][4] = {};
    int cl = lane & 15, kq = (lane >> 4) * 8;

    int nt = K >> 5;                          // K/32 tiles
    // prologue: stage tile 0 into buf 0
    gl2lds16(Ags, &Al[0][0] + wofs);
    gl2lds16(Ags + (size_t)64 * K, &Al[0][0] + 2048 + wofs);
    gl2lds16(Bgs, &Bl[0][0] + wofs);
    gl2lds16(Bgs + (size_t)64 * K, &Bl[0][0] + 2048 + wofs);
    __syncthreads();

    int cur = 0;
    for (int t = 0; t < nt; ++t) {
        if (t + 1 < nt) {                     // prefetch tile t+1 into buf cur^1
            int k1 = (t + 1) * 32;
            gl2lds16(Ags + k1, &Al[cur ^ 1][0] + wofs);
            gl2lds16(Ags + (size_t)64 * K + k1, &Al[cur ^ 1][0] + 2048 + wofs);
            gl2lds16(Bgs + k1, &Bl[cur ^ 1][0] + wofs);
            gl2lds16(Bgs + (size_t)64 * K + k1, &Bl[cur ^ 1][0] + 2048 + wofs);
        }
        bh8 af[4], bf[4];
#pragma unroll
        for (int mi = 0; mi < 4; ++mi)
            af[mi] = *(const bh8*)(&Al[cur][0] + (wm + mi * 16 + cl) * 32 + kq);
#pragma unroll
        for (int nj = 0; nj < 4; ++nj)
            bf[nj] = *(const bh8*)(&Bl[cur][0] + (wn + nj * 16 + cl) * 32 + kq);
#pragma unroll
        for (int mi = 0; mi < 4; ++mi)
#pragma unroll
            for (int nj = 0; nj < 4; ++nj)
                acc[mi][nj] = __builtin_amdgcn_mfma_f32_16x16x32_bf16(
                    af[mi], bf[nj], acc[mi][nj], 0, 0, 0);
        if (t + 1 < nt) __syncthreads();      // drains vmcnt (t+1 landed) + lgkm
        cur ^= 1;
    }

    int rb = (lane >> 4) * 4;
#pragma unroll
    for (int mi = 0; mi < 4; ++mi) {
#pragma unroll
        for (int nj = 0; nj < 4; ++nj) {
#pragma unroll
            for (int r = 0; r < 4; ++r) {
                int gm = m0 + wm + mi * 16 + rb + r;
                int gn = n0 + wn + nj * 16 + cl;
                float v = acc[mi][nj][r];
                if (MODE == 0) {
                    int b = gm >> 11, ls = gm & 2047;
                    int sel = gn >> 10, h = (gn >> 6) & 15, d = gn & 63;
                    if (sel == 0)   // Q pre-scaled by 1/sqrt(HD) (exact exp shift)
                        Qg[((size_t)(b * NH + h) * Lseq + ls) * HD + d] = f2bf(v * 0.125f);
                    else if (sel == 1)
                        Kg[((size_t)(b * NH + h) * Lseq + ls) * HD + d] = f2bf(v);
                    else  // V transposed: Vt[bh][d][kv]
                        Vg[((size_t)(b * NH + h) * HD + d) * Lseq + ls] = f2bf(v);
                } else {
                    Cf[(size_t)gm * OUTD + gn] = v;
                }
            }
        }
    }
}

// ---------------------------------------------------------------- causal flash attention
// (unchanged from R12/R13 — verified: LDS-staged K/V, XOR swizzle both sides,
// no-max softmax + ones-MFMA row-sum, XCD-affinity decode, paired tiles)
__global__ __launch_bounds__(256) void attn_causal(
    const unsigned short* __restrict__ Qg, const unsigned short* __restrict__ Kg,
    const unsigned short* __restrict__ Vt, unsigned short* __restrict__ Og) {
    __shared__ unsigned short Kl[64 * 64];        // 8 KB, swizzled rows
    __shared__ unsigned short Vl[64 * 64];        // 8 KB, swizzled rows
    __shared__ unsigned short Pl[4][16 * 72];     // per-wave P tile (9 KB)
    int tid = threadIdx.x, wave = tid >> 6, lane = tid & 63;
    int bid = blockIdx.x;
    int xcd = bid & 7, slot = bid >> 3;       // slot 0..127
    int p = slot & 15;                        // pair index 0..15
    int bh = ((slot >> 4) << 3) | xcd;        // bh in 0..63, bh%8==xcd
    int b = bh >> 4, h = bh & 15;
    const unsigned short* Qp = Qg + (size_t)bh * Lseq * HD;
    const unsigned short* Kp = Kg + (size_t)bh * Lseq * HD;
    const unsigned short* Vp = Vt + (size_t)bh * HD * Lseq;   // [d][kv]
    int cl = lane & 15, kq = (lane >> 4) * 8, rb = (lane >> 4) * 4;
    unsigned short* Pw = &Pl[wave][0];

    int srow = tid >> 2;                      // staging row 0..63
    int sc0 = (tid & 3) * 16;                 // element chunk base
    int ssw = (srow & 7) << 3;                // write-side swizzle (elements)

    bh8 ones;
#pragma unroll
    for (int i = 0; i < 8; ++i) ones[i] = (short)0x3F80;   // bf16 1.0

    for (int pass = 0; pass < 2; ++pass) {
        int pt = pass ? (31 - p) : p;
        int q0 = pt * 64 + wave * 16;         // this wave's 16 rows

        bh8 qf0 = *(const bh8*)(Qp + (size_t)(q0 + cl) * HD + kq);
        bh8 qf1 = *(const bh8*)(Qp + (size_t)(q0 + cl) * HD + 32 + kq);

        f32x4 o[4] = {};
        f32x4 osum = {};                      // P row-sums via ones-MFMA

        int nblk = pt + 1;                    // uniform across waves
        for (int j = 0; j < nblk; ++j) {
            int kv0 = j * 64;
            const unsigned short* Ks = Kp + (size_t)(kv0 + srow) * HD;
            const unsigned short* Vs = Vp + (size_t)srow * Lseq + kv0;
            bh8 k0 = *(const bh8*)(Ks + sc0);
            bh8 k1 = *(const bh8*)(Ks + sc0 + 8);
            bh8 v0 = *(const bh8*)(Vs + sc0);
            bh8 v1 = *(const bh8*)(Vs + sc0 + 8);
            __syncthreads();                  // prior iter's frag reads done
            *(bh8*)(Kl + srow * 64 + (sc0 ^ ssw)) = k0;
            *(bh8*)(Kl + srow * 64 + ((sc0 + 8) ^ ssw)) = k1;
            *(bh8*)(Vl + srow * 64 + (sc0 ^ ssw)) = v0;
            *(bh8*)(Vl + srow * 64 + ((sc0 + 8) ^ ssw)) = v1;
            __syncthreads();
#pragma unroll
            for (int nb = 0; nb < 4; ++nb) {
                int row = nb * 16 + cl, rs = (row & 7) << 3;
                bh8 kf0 = *(const bh8*)(Kl + row * 64 + (kq ^ rs));
                bh8 kf1 = *(const bh8*)(Kl + row * 64 + ((kq + 32) ^ rs));
                f32x4 s = {};
                s = __builtin_amdgcn_mfma_f32_16x16x32_bf16(qf0, kf0, s, 0, 0, 0);
                s = __builtin_amdgcn_mfma_f32_16x16x32_bf16(qf1, kf1, s, 0, 0, 0);
                int col = kv0 + nb * 16 + cl;
#pragma unroll
                for (int r = 0; r < 4; ++r) {
                    float v = s[r];                   // Q pre-scaled by 1/8
                    if (col > q0 + rb + r) v = -3e30f;    // causal mask
                    Pw[(rb + r) * 72 + nb * 16 + cl] = f2bf(__expf(v));
                }
            }
            bh8 pa0 = *(const bh8*)(Pw + cl * 72 + kq);
            bh8 pa1 = *(const bh8*)(Pw + cl * 72 + 32 + kq);
#pragma unroll
            for (int db = 0; db < 4; ++db) {
                int dr = db * 16 + cl, ds = (dr & 7) << 3;
                bh8 vf0 = *(const bh8*)(Vl + dr * 64 + (kq ^ ds));
                bh8 vf1 = *(const bh8*)(Vl + dr * 64 + ((kq + 32) ^ ds));
                o[db] = __builtin_amdgcn_mfma_f32_16x16x32_bf16(pa0, vf0, o[db], 0, 0, 0);
                o[db] = __builtin_amdgcn_mfma_f32_16x16x32_bf16(pa1, vf1, o[db], 0, 0, 0);
            }
            osum = __builtin_amdgcn_mfma_f32_16x16x32_bf16(pa0, ones, osum, 0, 0, 0);
            osum = __builtin_amdgcn_mfma_f32_16x16x32_bf16(pa1, ones, osum, 0, 0, 0);
        }
#pragma unroll
        for (int r = 0; r < 4; ++r) {
            float inv = 1.0f / osum[r];
            int row = q0 + rb + r;
            size_t obase = (size_t)(b * Lseq + row) * OUTD + h * HD;
#pragma unroll
            for (int db = 0; db < 4; ++db)
                Og[obase + db * 16 + cl] = f2bf(o[db][r] * inv);
        }
    }
}

// ---------------------------------------------------------------- launch
extern "C" void kernel_launch(void* const* d_in, const int* in_sizes, int n_in,
                              void* d_out, int out_size, void* d_ws, size_t ws_size,
                              hipStream_t stream) {
    (void)in_sizes; (void)n_in; (void)out_size; (void)ws_size;
    const float* X    = (const float*)d_in[0];
    const float* Wqkv = (const float*)d_in[1];
    const float* Wout = (const float*)d_in[2];
    float* out = (float*)d_out;

    char* ws = (char*)d_ws;
    size_t off = 0;
    unsigned short* Xb    = (unsigned short*)(ws + off); off += (size_t)Mrows * INDIM * 2;
    unsigned short* WqkvT = (unsigned short*)(ws + off); off += (size_t)QKVN * INDIM * 2;
    unsigned short* WoutT = (unsigned short*)(ws + off); off += (size_t)OUTD * (NH * HD) * 2;
    unsigned short* Qg    = (unsigned short*)(ws + off); off += (size_t)Mrows * NH * HD * 2;
    unsigned short* Kg    = (unsigned short*)(ws + off); off += (size_t)Mrows * NH * HD * 2;
    unsigned short* Vtg   = (unsigned short*)(ws + off); off += (size_t)Mrows * NH * HD * 2;
    unsigned short* Ob    = (unsigned short*)(ws + off); off += (size_t)Mrows * NH * HD * 2;

    convert_f32_bf16<<<(Mrows * INDIM / 8 + 255) / 256, 256, 0, stream>>>(
        X, Xb, Mrows * INDIM / 8);
    transpose_f32_bf16<<<dim3(QKVN / 64, INDIM / 64), 256, 0, stream>>>(
        Wqkv, WqkvT, INDIM, QKVN);
    transpose_f32_bf16<<<dim3(OUTD / 64, (NH * HD) / 64), 256, 0, stream>>>(
        Wout, WoutT, NH * HD, OUTD);
    gemm_bt<0><<<(Mrows / 128) * (QKVN / 128), 256, 0, stream>>>(
        Xb, WqkvT, nullptr, Qg, Kg, Vtg, INDIM, QKVN / 128);
    attn_causal<<<Bsz * NH * 16, 256, 0, stream>>>(Qg, Kg, Vtg, Ob);
    gemm_bt<1><<<(Mrows / 128) * (OUTD / 128), 256, 0, stream>>>(
        Ob, WoutT, out, nullptr, nullptr, nullptr, NH * HD, OUTD / 128);
}